// Round 7
// baseline (334.544 us; speedup 1.0000x reference)
//
#include <hip/hip_runtime.h>
#include <math.h>

// Problem constants (fixed by setup_inputs)
#define BB 32
#define NN 1024
#define DD 1024
#define HH 512

// out layout (floats): [one_hot 32*1024*1024][masked_acts 32*1024][kl 32][log_nom 32][log_norm 32]
#define OUT0_OFF 0
#define OUT1_OFF (BB * NN * NN)
#define OUT2_OFF (OUT1_OFF + BB * NN)
#define OUT3_OFF (OUT2_OFF + BB)
#define OUT4_OFF (OUT3_OFF + BB)

// ws layout (bytes): acts fp32 [32768] @0 ; W1T bf16 [512][1024] @131072 ; rank int[32768] @1179648
#define WS_ACTS 0
#define WS_W1T  131072
#define WS_RANK 1179648

typedef __attribute__((ext_vector_type(8))) short short8;
typedef __attribute__((ext_vector_type(4))) float floatx4;

__device__ inline unsigned int f2bf(float x) {  // RNE fp32 -> bf16 bits
    unsigned int u = __builtin_bit_cast(unsigned int, x);
    return (u + 0x7FFFu + ((u >> 16) & 1u)) >> 16;
}

// ---------------------------------------------------------------------------
// K0: transpose + convert W1 [d=1024][h=512] fp32 -> W1T [h=512][d=1024] bf16
// ---------------------------------------------------------------------------
__global__ __launch_bounds__(1024) void w1t_kernel(const float* __restrict__ W1,
                                                   unsigned short* __restrict__ W1T)
{
    __shared__ float T[32][33];
    const int tx = threadIdx.x, ty = threadIdx.y;
    const int d0 = blockIdx.x * 32, h0 = blockIdx.y * 32;
    T[ty][tx] = W1[(d0 + ty) * HH + h0 + tx];
    __syncthreads();
    W1T[(size_t)(h0 + ty) * DD + d0 + tx] = (unsigned short)f2bf(T[tx][ty]);
}

// ---------------------------------------------------------------------------
// K1: MFMA GEMM + fused relu/W2 epilogue.  ROUND-7: B fragments DIRECT from L2.
// Rounds 0-6: six schedule/geometry variants (same-iter drain, rotated drain,
// counted vmcnt, 2x occupancy, BK=64 wave-private B) ALL converge to 84-89 us,
// MfmaUtil ~15.5% -- the cost is in the machinery common to all six, not the
// schedule: global_load_lds + manual vmcnt ledger + "memory"-clobber asm
// fences that pin hipcc's scheduler (m141 lesson), + setprio (m190: hurts
// non-phase-split GEMM).  W1T is 1 MB = L2-resident on every XCD, and its
// MFMA B-fragment is directly addressable: lane (c,qd) of tile tn reads 16 B
// at row(n)*2048 + k0*2 + qd*16 -- the same 16x64B L2 lines as the DMA path,
// zero LDS round-trip.  So B's LDS path is DELETED.  Only A (needs fp32->bf16
// pack + cross-wave sharing) stays in LDS, double-buffered, ONE __syncthreads
// per 64-K period (16 total).  No inline asm in the loop: every wait is
// compiler-inserted (the m97 regime, where hipcc's scheduling is known-good).
// Fragment contents and K-order are bit-identical to rounds 5/6 (passing).
// Geometry: 512 threads (8 waves), MT=64, wave w owns cols w*64..+64, all 64
// rows; acc[4][4] = 64 AGPR.  LDS = 2x8K A + 2K red = 18 KB.
// Regs ~130 @ launch_bounds(512,4); tripwire: spill shows as WRITE_SIZE >>256K.
// ---------------------------------------------------------------------------
#define MT 64

__global__ __launch_bounds__(512, 4) void gemm_acts_kernel(
    const float* __restrict__ q, const unsigned short* __restrict__ W1T,
    const float* __restrict__ b1, const float* __restrict__ W2,
    const float* __restrict__ b2, const float* __restrict__ unoise,
    float* __restrict__ acts_ws, float* __restrict__ out1)
{
    __shared__ short As[2][MT * 64];   // 2 x 8192 B (64 rows x 128 B, swizzled)
    __shared__ float red[MT][8];

    const int tid  = threadIdx.x;
    const int w    = tid >> 6;         // wave 0..7
    const int lane = tid & 63;
    const int c    = lane & 15;        // fragment row/col-in-tile
    const int qd   = lane >> 4;        // quad 0..3
    const int m0   = blockIdx.x * MT;

    floatx4 acc[4][4];
    #pragma unroll
    for (int tn = 0; tn < 4; ++tn)
        #pragma unroll
        for (int tm = 0; tm < 4; ++tm)
            acc[tn][tm] = (floatx4){0.f, 0.f, 0.f, 0.f};

    // B direct-load bases: 16-B units into W1T; row n = w*64 + tn*16 + c has
    // 128 units; k-slice qd within each 64-elem chunk.  Per sub-step the unit
    // index is bunit[tn] + 8*s (+4 for the second 32-K half).
    const short8* w1ts = (const short8*)W1T;
    int bunit[4];
    #pragma unroll
    for (int tn = 0; tn < 4; ++tn)
        bunit[tn] = (w * 64 + tn * 16 + c) * 128 + qd;

    // A staging (verified in rounds 5/6): thread -> row arow = tid>>3 (0..63),
    // group agrp = tid&7.  Stored byte b of a row holds element byte
    // b ^ ((arow&7)<<4): write side realized by pre-XOR'd SOURCE group.
    const int arow = tid >> 3;
    const int agrp = tid & 7;
    const float* aptrA = q + (size_t)(m0 + arow) * DD + ((agrp ^ (arow & 7)) * 8);
    const int adst = arow * 128 + agrp * 16;   // linear dst byte

    // A frag-read byte offsets: sub0 slot qd^(r&7), sub1 slot (4+qd)^(r&7)
    int aoffA[4], aoffB[4];
    #pragma unroll
    for (int tm = 0; tm < 4; ++tm) {
        int r = tm * 16 + c;
        aoffA[tm] = r * 128 + 16 * ((qd)     ^ (r & 7));
        aoffB[tm] = r * 128 + 16 * ((4 + qd) ^ (r & 7));
    }

    float4 a0, a1;

    // ---- prologue: pack A(0) -> As[0]; preload A(1) regs ----
    {
        float4 v0 = *(const float4*)(aptrA + 0);
        float4 v1 = *(const float4*)(aptrA + 4);
        uint4 pk;
        pk.x = f2bf(v0.x) | (f2bf(v0.y) << 16);
        pk.y = f2bf(v0.z) | (f2bf(v0.w) << 16);
        pk.z = f2bf(v1.x) | (f2bf(v1.y) << 16);
        pk.w = f2bf(v1.z) | (f2bf(v1.w) << 16);
        *(uint4*)((char*)(&As[0][0]) + adst) = pk;
        a0 = *(const float4*)(aptrA + 64);
        a1 = *(const float4*)(aptrA + 64 + 4);
    }

    #pragma unroll 1
    for (int s = 0; s < 16; ++s) {
        const int p = s & 1;
        const char* asP = (const char*)(&As[p][0]);
        char*       asN = (char*)(&As[p ^ 1][0]);
        // One barrier per 64-K period: makes As[p] (packed last period)
        // visible, and guarantees last period's readers of As[p^1] are done
        // (their ds_reads retired before each wave's MFMAs, which precede the
        // barrier in program order).
        __syncthreads();

        // ---- sub-step 0: K range [64s, 64s+32) ----
        {
            short8 bf[4];
            #pragma unroll
            for (int tn = 0; tn < 4; ++tn)
                bf[tn] = w1ts[bunit[tn] + 8 * s];      // direct from L2
            #pragma unroll
            for (int tm = 0; tm < 4; ++tm) {
                short8 af = *(const short8*)(asP + aoffA[tm]);
                #pragma unroll
                for (int tn = 0; tn < 4; ++tn)
                    acc[tn][tm] = __builtin_amdgcn_mfma_f32_16x16x32_bf16(
                        af, bf[tn], acc[tn][tm], 0, 0, 0);
            }
        }

        // pack A(s+1) -> As[p^1]; issue A loads (s+2)
        if (s < 15) {
            uint4 pk;
            pk.x = f2bf(a0.x) | (f2bf(a0.y) << 16);
            pk.y = f2bf(a0.z) | (f2bf(a0.w) << 16);
            pk.z = f2bf(a1.x) | (f2bf(a1.y) << 16);
            pk.w = f2bf(a1.z) | (f2bf(a1.w) << 16);
            *(uint4*)(asN + adst) = pk;
            const int ka = (s < 14) ? s + 2 : 15;   // clamped dummy at s=14
            a0 = *(const float4*)(aptrA + ka * 64);
            a1 = *(const float4*)(aptrA + ka * 64 + 4);
        }

        // ---- sub-step 1: K range [64s+32, 64s+64) ----
        {
            short8 bf[4];
            #pragma unroll
            for (int tn = 0; tn < 4; ++tn)
                bf[tn] = w1ts[bunit[tn] + 8 * s + 4];
            #pragma unroll
            for (int tm = 0; tm < 4; ++tm) {
                short8 af = *(const short8*)(asP + aoffB[tm]);
                #pragma unroll
                for (int tn = 0; tn < 4; ++tn)
                    acc[tn][tm] = __builtin_amdgcn_mfma_f32_16x16x32_bf16(
                        af, bf[tn], acc[tn][tm], 0, 0, 0);
            }
        }
    }

    // epilogue: h = relu(acc + b1); rowsum += h*W2; reduce 16 cols + 8 waves
    float b1v[4], w2v[4];
    #pragma unroll
    for (int tn = 0; tn < 4; ++tn) {
        int col = w * 64 + tn * 16 + c;
        b1v[tn] = b1[col];
        w2v[tn] = W2[col];
    }
    #pragma unroll
    for (int tm = 0; tm < 4; ++tm) {
        #pragma unroll
        for (int r = 0; r < 4; ++r) {
            float p = 0.f;
            #pragma unroll
            for (int tn = 0; tn < 4; ++tn) {
                float v = acc[tn][tm][r] + b1v[tn];
                p = fmaf(fmaxf(v, 0.f), w2v[tn], p);
            }
            p += __shfl_xor(p, 1);
            p += __shfl_xor(p, 2);
            p += __shfl_xor(p, 4);
            p += __shfl_xor(p, 8);
            if (c == 0) red[tm * 16 + qd * 4 + r][w] = p;
        }
    }
    __syncthreads();
    if (tid < MT) {
        float raw = red[tid][0] + red[tid][1] + red[tid][2] + red[tid][3] +
                    red[tid][4] + red[tid][5] + red[tid][6] + red[tid][7] + b2[0];
        float sp = fmaxf(raw, 0.f) + log1pf(expf(-fabsf(raw)));  // stable softplus
        int row = m0 + tid;
        float av = logf(fmaxf(sp, 1e-5f)) + unoise[row];
        acts_ws[row] = av;
        out1[row]    = av;
    }
}

// ---------------------------------------------------------------------------
// K2: zero the one-hot output region
// ---------------------------------------------------------------------------
__global__ __launch_bounds__(256) void zero_kernel(float4* __restrict__ p, int n4)
{
    int idx = blockIdx.x * blockDim.x + threadIdx.x;
    int stride = gridDim.x * blockDim.x;
    float4 z = make_float4(0.f, 0.f, 0.f, 0.f);
    for (int i = idx; i < n4; i += stride) p[i] = z;
}

// ---------------------------------------------------------------------------
// K3: rank-by-counting, spread across 128 blocks (4 per batch, 256 i each)
// ---------------------------------------------------------------------------
__global__ __launch_bounds__(256) void rank_kernel(
    const float* __restrict__ acts_ws, const float* __restrict__ gumbel,
    int* __restrict__ rank)
{
    __shared__ float P[NN];
    const int b = blockIdx.x >> 2;
    const int chunk = blockIdx.x & 3;
    const int tid = threadIdx.x;
    #pragma unroll
    for (int r = 0; r < 4; ++r) {
        int j = r * 256 + tid;
        P[j] = acts_ws[b * NN + j] + gumbel[b * NN + j];
    }
    __syncthreads();
    const int i = chunk * 256 + tid;
    const float pert = P[i];
    int cnt = 0;
    const float4* P4 = (const float4*)P;
    for (int j4 = 0; j4 < NN / 4; ++j4) {
        float4 pv = P4[j4];  // broadcast
        int j = j4 * 4;
        cnt += (pv.x > pert) || (pv.x == pert && j + 0 < i);
        cnt += (pv.y > pert) || (pv.y == pert && j + 1 < i);
        cnt += (pv.z > pert) || (pv.z == pert && j + 2 < i);
        cnt += (pv.w > pert) || (pv.w == pert && j + 3 < i);
    }
    rank[b * NN + i] = cnt;
}

// ---------------------------------------------------------------------------
// K4: per-batch permutation, one-hot scatter, PL likelihood, kl.
// Wave-level shfl suffix-scan + butterfly reductions: 4 block barriers total.
// ---------------------------------------------------------------------------
__global__ __launch_bounds__(1024) void permu_stats_kernel(
    const float* __restrict__ acts_ws, const int* __restrict__ rank,
    float* __restrict__ out0, float* __restrict__ out2,
    float* __restrict__ out3, float* __restrict__ out4)
{
    __shared__ float A[NN];
    __shared__ int   IDX[NN];
    __shared__ float WT[16];
    __shared__ float WSUF[17];
    __shared__ float P0[16], P1[16], P2[16];

    const int b = blockIdx.x;
    const int i = threadIdx.x;
    const int lane = i & 63;
    const int w = i >> 6;            // wave 0..15

    float a = acts_ws[b * NN + i];
    A[i] = a;
    IDX[rank[b * NN + i]] = i;
    __syncthreads();                                        // barrier A

    int perm = (i == 0) ? 0 : IDX[i - 1];
    out0[((size_t)b * NN + i) * NN + perm] = 1.0f;

    float e = expf(A[perm]);
    // intra-wave inclusive suffix sum of e
    float s = e;
    #pragma unroll
    for (int off = 1; off < 64; off <<= 1) {
        float v = __shfl_down(s, off);
        if (lane + off < 64) s += v;
    }
    if (lane == 0) WT[w] = s;        // wave total (suffix from lane 0)
    __syncthreads();                                        // barrier B
    if (w == 0) {
        float t = (lane < 16) ? WT[lane] : 0.f;
        #pragma unroll
        for (int off = 1; off < 16; off <<= 1) {
            float v = __shfl_down(t, off);
            if (lane + off < 16) t += v;
        }
        if (lane < 16) WSUF[lane] = t;   // sum over waves >= lane
        if (lane == 0) WSUF[16] = 0.f;
    }
    __syncthreads();                                        // barrier C

    float S = s + WSUF[w + 1];       // full suffix sum_{j>=i} e_j
    float term = logf(e + 1e-20f) - logf(S + 1e-20f);

    // three simultaneous full-wave butterfly reductions
    float r0 = term, r1 = a, r2 = expf(-fmaxf(a, -20.f));
    #pragma unroll
    for (int off = 1; off < 64; off <<= 1) {
        r0 += __shfl_xor(r0, off);
        r1 += __shfl_xor(r1, off);
        r2 += __shfl_xor(r2, off);
    }
    if (lane == 0) { P0[w] = r0; P1[w] = r1; P2[w] = r2; }
    __syncthreads();                                        // barrier D
    if (i == 0) {
        float t0 = 0.f, t1 = 0.f, t2 = 0.f;
        #pragma unroll
        for (int k = 0; k < 16; ++k) { t0 += P0[k]; t1 += P1[k]; t2 += P2[k]; }
        out3[b] = t0;
        out2[b] = -(float)NN + t1 + t2;
        out4[b] = 0.f;
    }
}

extern "C" void kernel_launch(void* const* d_in, const int* in_sizes, int n_in,
                              void* d_out, int out_size, void* d_ws, size_t ws_size,
                              hipStream_t stream)
{
    const float* q      = (const float*)d_in[0];
    const float* W1     = (const float*)d_in[2];
    const float* b1     = (const float*)d_in[3];
    const float* W2     = (const float*)d_in[4];
    const float* b2     = (const float*)d_in[5];
    const float* unoise = (const float*)d_in[6];
    const float* gumbel = (const float*)d_in[7];

    float* out  = (float*)d_out;
    char*  ws   = (char*)d_ws;
    float*          acts = (float*)(ws + WS_ACTS);
    unsigned short* W1T  = (unsigned short*)(ws + WS_W1T);
    int*            rank = (int*)(ws + WS_RANK);

    w1t_kernel<<<dim3(32, 16), dim3(32, 32), 0, stream>>>(W1, W1T);
    gemm_acts_kernel<<<(BB * NN) / MT, 512, 0, stream>>>(q, W1T, b1, W2, b2,
                                                         unoise, acts,
                                                         out + OUT1_OFF);
    zero_kernel<<<8192, 256, 0, stream>>>((float4*)(out + OUT0_OFF),
                                          (BB * NN * NN) / 4);
    rank_kernel<<<BB * 4, 256, 0, stream>>>(acts, gumbel, rank);
    permu_stats_kernel<<<BB, 1024, 0, stream>>>(acts, rank,
                                                out + OUT0_OFF, out + OUT2_OFF,
                                                out + OUT3_OFF, out + OUT4_OFF);
}